// Round 10
// baseline (99.150 us; speedup 1.0000x reference)
//
#include <hip/hip_runtime.h>

#define SEQ   512
#define BATCH 256

// Lane broadcast via v_readlane (imm or SGPR index).
__device__ __forceinline__ float bcast_f(float v, int l) {
    return __int_as_float(__builtin_amdgcn_readlane(__float_as_int(v), l));
}
// gfx950: v_log_f32 is log2, v_exp_f32 is exp2.
__device__ __forceinline__ float flog2(float x) { return __builtin_amdgcn_logf(x); }
__device__ __forceinline__ float fexp2(float x) { return __builtin_amdgcn_exp2f(x); }
// Barrier draining only LDS ops (lgkmcnt), not vmcnt.
__device__ __forceinline__ void lds_barrier() {
    __asm__ __volatile__("s_waitcnt lgkmcnt(0)\ns_barrier" ::: "memory");
}

// Apply N columns [start, start+N) of column block K to row block R.
// p_lds holds published p_j = -(a + c*expm_j): term = exp2(p * log2(max(dx,1))).
template<int N>
__device__ __forceinline__ void pair_n(int K, int R, int lane, int start,
                                       const float* x_lds, const float* p_lds,
                                       float (*part_lds)[64]) {
    const float pvec = p_lds[(K << 6) | lane];
    const float xjv  = x_lds[(K << 6) | lane];
    const float xr   = x_lds[(R << 6) | lane];
    float pacc = 0.0f;
#pragma unroll
    for (int k = 0; k < N; ++k) {
        const float p  = bcast_f(pvec, start + k);
        const float xj = bcast_f(xjv, start + k);
        const float L  = flog2(fmaxf(xr - xj, 1.0f));
        pacc += fexp2(p * L);
    }
    atomicAdd(&part_lds[R][lane], pacc);
}

// One block (1024 threads = 16 waves, 4 waves/SIMD) per batch column.
// Wave 0: serial diagonal (readlane-carry chain). Waves 1..15: helpers, each
// owning a fixed column slice (SIMD0-resident waves 4/8/12 are "light").
// Phase J, segment A (before B1): panel (J-1 -> J) + A-deep (J-1, J+1).
// Segment B (with diag J): 3 scheduled B-deep pairs. All 28 pairs placed
// once, inside their legal publish/consume windows. Partials merge via LDS
// atomicAdd into part_lds[R]; wave0 reads part_lds[J] once after B1.
// Maskless diag: lanes i<=jl add exactly 1.0/step; subtract (64-lane) once.
__global__ void __launch_bounds__(1024, 1)
act_r_kernel(const float* __restrict__ sp, const float* __restrict__ w,
             float* __restrict__ out) {
    __shared__ float x_lds[SEQ];
    __shared__ float p_lds[SEQ];       // published -(a + c*expm)
    __shared__ float expm_lds[SEQ];    // published expm (epilogue)
    __shared__ float part_lds[8][64];  // [row block][lane]

    const int b    = blockIdx.x;
    const int tid  = threadIdx.x;
    const int wid  = tid >> 6;
    const int lane = tid & 63;

    const float a = w[0], c = w[1], s = w[2], tau = w[3], h = w[4];
    const float scale = 86400.0f * h;

    // Column slices: lights (waves 4,8,12 on SIMD0) 4 cols; others 4-5.
    const int SSTART[16] = {0, 12,17,22, 0, 27,32,36, 4, 40,44,48, 8, 52,56,60};
    const int SCNT[16]   = {0,  5, 5, 5, 4,  5, 4, 4, 4,  4, 4, 4, 4,  4, 4, 4};
    const int start = SSTART[wid];
    const int cnt   = SCNT[wid];

    if (tid < SEQ) x_lds[tid] = sp[tid * BATCH + b] * scale;
    else           ((float*)part_lds)[tid - SEQ] = 0.0f;   // 512 floats
    lds_barrier();

    auto do_pair = [&](int K, int R) {
        if (cnt == 5) pair_n<5>(K, R, lane, start, x_lds, p_lds, part_lds);
        else          pair_n<4>(K, R, lane, start, x_lds, p_lds, part_lds);
    };

    // B-segment deep schedule (3 pairs/phase, J = 1..5).
    const int BN[8]     = {0,3,3,3,3,3,0,0};
    const int BKt[8][3] = {{0,0,0},{0,0,0},{1,1,0},{2,1,0},{2,3,1},{2,3,4},{0,0,0},{0,0,0}};
    const int BRt[8][3] = {{0,0,0},{3,4,5},{4,5,6},{5,6,7},{6,6,7},{7,7,7},{0,0,0},{0,0,0}};

#pragma unroll
    for (int J = 0; J < 8; ++J) {
        // ---- segment A: panel + A-deep (helpers); wave0 idles
        if (cnt > 0 && J > 0) {
            do_pair(J - 1, J);                      // panel (needed at B1)
            if (J <= 6) do_pair(J - 1, J + 1);      // A-deep
        }
        lds_barrier();  // B1: part_lds[J] complete

        if (wid == 0) {
            float acc = part_lds[J][lane];          // merged off-diag base
            const float xd = x_lds[(J << 6) | lane];
            const float na = -a, nc = -c;
            // serial chain: readlane -> fma -> exp2 -> add (log off-chain)
#pragma unroll
            for (int jl = 0; jl < 64; ++jl) {
                const float sj  = bcast_f(xd, jl);
                const float L   = flog2(fmaxf(xd - sj, 1.0f));
                const float nAL = na * L;
                const float nCL = nc * L;
                const float em  = bcast_f(acc, jl);
                acc += fexp2(fmaf(nCL, em, nAL));
            }
            const float clean = acc - (float)(64 - lane);
            expm_lds[(J << 6) | lane] = clean;
            p_lds[(J << 6) | lane]    = -fmaf(c, clean, a);   // publish p
        } else if (cnt > 0) {
            // ---- segment B: scheduled deep pairs (overlap the diagonal)
            for (int t2 = 0; t2 < BN[J]; ++t2)
                do_pair(BKt[J][t2], BRt[J][t2]);
        }
        lds_barrier();  // B2: expm/p block J published
    }

    // ---- epilogue: threads 1..511 produce out rows 0..510
    if (tid >= 1 && tid < SEQ) {
        const float inv_ln2 = 1.4426950408889634f;
        const float q = tau / s * inv_ln2 - flog2(expm_lds[tid]) / s;
        out[(tid - 1) * BATCH + b] = 1.0f / (1.0f + fexp2(q));
    }
}

extern "C" void kernel_launch(void* const* d_in, const int* in_sizes, int n_in,
                              void* d_out, int out_size, void* d_ws, size_t ws_size,
                              hipStream_t stream) {
    const float* sp = (const float*)d_in[0];  // [512, 256, 1] f32
    const float* w  = (const float*)d_in[1];  // [5] f32
    float* out = (float*)d_out;               // [511, 256, 1] f32
    (void)in_sizes; (void)n_in; (void)out_size; (void)d_ws; (void)ws_size;

    act_r_kernel<<<dim3(BATCH), dim3(1024), 0, stream>>>(sp, w, out);
}

// Round 11
// 81.083 us; speedup vs baseline: 1.2228x; 1.2228x over previous
//
#include <hip/hip_runtime.h>

#define SEQ   512
#define BATCH 256

// Lane broadcast via v_readlane (immediate index after unroll).
__device__ __forceinline__ float bcast_f(float v, int l) {
    return __int_as_float(__builtin_amdgcn_readlane(__float_as_int(v), l));
}
// gfx950: v_log_f32 is log2, v_exp_f32 is exp2.
__device__ __forceinline__ float flog2(float x) { return __builtin_amdgcn_logf(x); }
__device__ __forceinline__ float fexp2(float x) { return __builtin_amdgcn_exp2f(x); }

#define PACK8(a0,a1,a2,a3,a4,a5,a6,a7) \
    ( ((unsigned long long)(a0))       | ((unsigned long long)(a1) << 6)  \
    | ((unsigned long long)(a2) << 12) | ((unsigned long long)(a3) << 18) \
    | ((unsigned long long)(a4) << 24) | ((unsigned long long)(a5) << 30) \
    | ((unsigned long long)(a6) << 36) | ((unsigned long long)(a7) << 42) )

// One block (256 threads = 4 waves, 1/SIMD) per batch column. NO barriers
// after init, no atomics: row-block ownership + flag pipeline.
//   Wave w owns row blocks {w, 7-w}; their accumulators live in registers.
//   Owner of block K: precompute diag/panel logs (flag-independent) -> spin
//   flag[K-1] -> panel exp loop -> 64-step serial chain -> publish p-block K
//   (p_j = -(a+c*expm_j)) + flag[K] -> epilogue for its rows.
//   Deep sweeps (col block K -> owned row block R>=K+2) gated on flag[K],
//   statically ordered per wave (balanced: 7 sweep-equivalents per wave).
// Maskless diag: lanes i<=j give L=0 -> term=1.0 exactly; carry readlane at
// step j precedes lane j's first contamination; subtract (64-lane) at end.
__global__ void __launch_bounds__(256, 1)
act_r_kernel(const float* __restrict__ sp, const float* __restrict__ w,
             float* __restrict__ out) {
    __shared__ float x_lds[SEQ];
    __shared__ float p_lds[SEQ];
    __shared__ int   flag_lds[8];

    const int b    = blockIdx.x;
    const int tid  = threadIdx.x;
    const int wid  = tid >> 6;
    const int lane = tid & 63;

    volatile int* flag = flag_lds;

    const float a = w[0], c = w[1], s = w[2], tau = w[3], h = w[4];
    const float scale = 86400.0f * h;

    if (tid < 8) flag_lds[tid] = 0;
    x_lds[tid]       = sp[tid * BATCH + b] * scale;
    x_lds[tid + 256] = sp[(tid + 256) * BATCH + b] * scale;
    __syncthreads();   // the only barrier

    const int A = wid, B = 7 - wid;
    const float xA = x_lds[(A << 6) | lane];
    const float xB = x_lds[(B << 6) | lane];
    float accA = 0.0f, accB = 0.0f;

    const float k1 = tau / s * 1.4426950408889634f;
    const float k2 = 1.0f / s;
    const float na = -a, nc = -c;

    // ---- diag phase for block K (owner only)
    auto diag_phase = [&](int K, float& acc, float xd) {
        float Ld[64];                       // diag logs (no flag needed)
#pragma unroll
        for (int j = 0; j < 64; ++j)
            Ld[j] = flog2(fmaxf(xd - bcast_f(xd, j), 1.0f));
        if (K > 0) {
            const int Kp = K - 1;
            const float xc = x_lds[(Kp << 6) | lane];
            float Lp[64];                   // panel logs (no flag needed)
#pragma unroll
            for (int j = 0; j < 64; ++j)
                Lp[j] = flog2(fmaxf(xd - bcast_f(xc, j), 1.0f));
            while (flag[Kp] == 0) {}        // acquire
            __asm__ __volatile__("" ::: "memory");
            const float pv = p_lds[(Kp << 6) | lane];
            float s0 = 0.0f, s1 = 0.0f;
#pragma unroll
            for (int j = 0; j < 64; j += 2) {
                s0 += fexp2(bcast_f(pv, j)     * Lp[j]);
                s1 += fexp2(bcast_f(pv, j + 1) * Lp[j + 1]);
            }
            acc += s0 + s1;
        }
        // serial chain: readlane -> fma -> mul -> exp2 -> add
#pragma unroll
        for (int j = 0; j < 64; ++j) {
            const float em = bcast_f(acc, j);
            acc += fexp2(fmaf(nc, em, na) * Ld[j]);
        }
        const float clean = acc - (float)(64 - lane);
        p_lds[(K << 6) | lane] = -fmaf(c, clean, a);
        __asm__ __volatile__("s_waitcnt lgkmcnt(0)" ::: "memory");  // release
        flag[K] = 1;
        const int i = (K << 6) | lane;      // epilogue for owned rows
        if (i >= 1) {
            const float q = k1 - k2 * flog2(clean);
            out[(i - 1) * BATCH + b] = 1.0f / (1.0f + fexp2(q));
        }
    };

    // ---- deep sweep: col block K -> owned row block (acc, xr)
    auto sweep = [&](int K, float& acc, float xr) {
        while (flag[K] == 0) {}             // acquire
        __asm__ __volatile__("" ::: "memory");
        const float pv = p_lds[(K << 6) | lane];
        const float xc = x_lds[(K << 6) | lane];
        float s0 = 0.0f, s1 = 0.0f;
#pragma unroll
        for (int j = 0; j < 64; j += 2) {
            s0 += fexp2(bcast_f(pv, j)     * flog2(fmaxf(xr - bcast_f(xc, j),     1.0f)));
            s1 += fexp2(bcast_f(pv, j + 1) * flog2(fmaxf(xr - bcast_f(xc, j + 1), 1.0f)));
        }
        acc += s0 + s1;
    };

    // ---- static schedules: action = K*8 + R; R==K -> diag, else sweep(K->R)
    unsigned long long sched;
    int nact;
    if (wid == 0)      { sched = PACK8(0, 7, 15, 23, 31, 39, 47, 63); nact = 8; }
    else if (wid == 1) { sched = PACK8(9, 6, 14, 22, 30, 38, 54, 0);  nact = 7; }
    else if (wid == 2) { sched = PACK8(2, 18, 5, 13, 21, 29, 45, 0);  nact = 7; }
    else               { sched = PACK8(3, 11, 27, 4, 12, 20, 36, 0);  nact = 7; }

    for (int t = 0; t < nact; ++t) {
        const int act = (int)((sched >> (6 * t)) & 63ull);
        const int K = act >> 3, R = act & 7;
        if (K == R) {
            if (R == A) diag_phase(K, accA, xA);
            else        diag_phase(K, accB, xB);
        } else {
            if (R == A) sweep(K, accA, xA);
            else        sweep(K, accB, xB);
        }
    }
}

extern "C" void kernel_launch(void* const* d_in, const int* in_sizes, int n_in,
                              void* d_out, int out_size, void* d_ws, size_t ws_size,
                              hipStream_t stream) {
    const float* sp = (const float*)d_in[0];  // [512, 256, 1] f32
    const float* w  = (const float*)d_in[1];  // [5] f32
    float* out = (float*)d_out;               // [511, 256, 1] f32
    (void)in_sizes; (void)n_in; (void)out_size; (void)d_ws; (void)ws_size;

    act_r_kernel<<<dim3(BATCH), dim3(256), 0, stream>>>(sp, w, out);
}